// Round 15
// baseline (208.160 us; speedup 1.0000x reference)
//
#include <hip/hip_runtime.h>
#include <hip/hip_bf16.h>
#include <stdint.h>

#define DIM_ 2048
#define L_   2048
#define B_   2
#define H_   16
#define DH_  128
#define NT_  32   // K tiles of 64

// scale folded into Wq: (1/sqrt(128)) * log2(e)  -> softmax uses raw v_exp_f32
#define QSCALE_ 0.12751743f

typedef __attribute__((ext_vector_type(4))) float fp32x4;
typedef __attribute__((ext_vector_type(8))) short s16x8;

__device__ __forceinline__ unsigned short bf16_rne(float f) {
    unsigned u = __builtin_bit_cast(unsigned, f);
    u += 0x7fffu + ((u >> 16) & 1u);
    return (unsigned short)(u >> 16);
}

__device__ __forceinline__ fp32x4 MFMA(s16x8 a, s16x8 b, fp32x4 c) {
    return __builtin_amdgcn_mfma_f32_16x16x32_bf16(a, b, c, 0, 0, 0);
}

__device__ __forceinline__ void gld16(const void* g, void* l) {
    auto gp = reinterpret_cast<const uint32_t __attribute__((address_space(1)))*>(
        reinterpret_cast<uintptr_t>(g));
    auto lp = reinterpret_cast<uint32_t __attribute__((address_space(3)))*>(
        reinterpret_cast<uintptr_t>(l));
    __builtin_amdgcn_global_load_lds(gp, lp, 16, 0, 0);
}

__device__ __forceinline__ float exp2_raw(float x) {
    float r; asm("v_exp_f32 %0, %1" : "=v"(r) : "v"(x)); return r;
}

__device__ __forceinline__ unsigned cvtpk_bf16(float a, float b) {
    unsigned r; asm("v_cvt_pk_bf16_f32 %0, %1, %2" : "=v"(r) : "v"(a), "v"(b)); return r;
}

// ---------------------------------------------------------------------------
// Merged f32->bf16 conversion: query | value | Wq(*QSCALE_) | Wk | Wv
// (round-10 version — weights pre-converted ONCE; they are re-read 16x by the
//  GEMMs, so pre-conversion halves the repeated traffic. Round-14's in-GEMM
//  conversion regressed for exactly this reason.)
// ---------------------------------------------------------------------------
__global__ void __launch_bounds__(256)
cvt_all(const float* __restrict__ query, const float* __restrict__ value,
        const float* __restrict__ Wq, const float* __restrict__ Wk,
        const float* __restrict__ Wv,
        unsigned short* __restrict__ qb, unsigned short* __restrict__ vb,
        unsigned short* __restrict__ wqb, unsigned short* __restrict__ wkb,
        unsigned short* __restrict__ wvb)
{
    const int total4 = 7340032;
    int i = blockIdx.x * 256 + threadIdx.x;
    const int stride = gridDim.x * 256;
    for (; i < total4; i += stride) {
        const float4* s; ushort4* d; int off; float sc = 1.0f;
        if (i < 2097152)      { s = (const float4*)query; d = (ushort4*)qb;  off = i; }
        else if (i < 4194304) { s = (const float4*)value; d = (ushort4*)vb;  off = i - 2097152; }
        else if (i < 5242880) { s = (const float4*)Wq;    d = (ushort4*)wqb; off = i - 4194304; sc = QSCALE_; }
        else if (i < 6291456) { s = (const float4*)Wk;    d = (ushort4*)wkb; off = i - 5242880; }
        else                  { s = (const float4*)Wv;    d = (ushort4*)wvb; off = i - 6291456; }
        float4 v = s[off];
        ushort4 o;
        o.x = bf16_rne(v.x * sc); o.y = bf16_rne(v.y * sc);
        o.z = bf16_rne(v.z * sc); o.w = bf16_rne(v.w * sc);
        d[off] = o;
    }
}

// ---------------------------------------------------------------------------
// Merged projection GEMM: one grid-512 launch; role = p&1 after XCD swizzle.
// role 0 (q): round-10 qgemm body — 256x128, 3-buf, counted vmcnt(6)/tile.
// role 1 (kv): round-10 kvgemm body — A staged once, Bk+Bv, 2-buf, 1 barrier.
// LDS: 144KB union (q: 3x32K A + 3x16K B; kv: 2x32K A + 2x16K Bk + 2x16K Bv).
// Removes the inter-GEMM full-grid drain + launch gap of the split version.
// ---------------------------------------------------------------------------
__global__ void __launch_bounds__(512, 2)
projgemm(const unsigned short* __restrict__ qb, const unsigned short* __restrict__ vb,
         const unsigned short* __restrict__ wqb, const unsigned short* __restrict__ wkb,
         const unsigned short* __restrict__ wvb, const float* __restrict__ mask,
         unsigned short* __restrict__ q_ws, unsigned short* __restrict__ k_ws,
         unsigned short* __restrict__ v_ws)
{
    __shared__ __align__(16) char LDS[147456];

    const int tid  = threadIdx.x;
    const int lane = tid & 63;
    const int wid  = tid >> 6;
    const int wm   = wid >> 1;
    const int wn   = wid & 1;
    const int lr   = lane & 15;
    const int lg   = lane >> 4;

    const int p    = (blockIdx.x & 7) * 64 + (blockIdx.x >> 3);  // XCD swizzle, 512%8==0
    const int role = p & 1;
    const int rb   = p >> 1;                                      // 0..255
    const int bm   = (rb >> 4) << 8;
    const int bn   = (rb & 15) << 7;

    const int srow = tid >> 3;
    const int scol = ((tid & 7) ^ ((tid >> 3) & 7)) * 8;
    const int ldst = wid * 1024;

    const int r7   = (lr & 7) << 4;
    const int arow = (wm * 64 + lr) * 128;
    const int brow = (wn * 64 + lr) * 128;
    const int off0 = (lg << 4) ^ r7;
    const int off1 = (64 | (lg << 4)) ^ r7;

    const int bb = bm >> 11;
    const size_t bh0 = (size_t)(bb * H_) * (L_ * DH_);
    const int rbase = bm + wm * 64;
    const int cbase = bn + wn * 64;

    if (role == 0) {
        // ---------------- Q GEMM (round-10 qgemm body) ----------------
        // LDS: A = LDS + buf*32768 (3 bufs), B = LDS + 98304 + buf*16384 (3 bufs)
        const unsigned short* gA = qb  + (size_t)(bm + srow) * DIM_ + scol;
        const unsigned short* gB = wqb + (size_t)(bn + srow) * DIM_ + scol;

        fp32x4 acc[4][4] = {};

#define QA(BUF) (LDS + (BUF) * 32768)
#define QB(BUF) (LDS + 98304 + (BUF) * 16384)
#define STG6(BUF, T) do {                                                         \
    gld16(gA + (size_t)(T) * 64,                 QA(BUF) + ldst);                 \
    gld16(gA + (size_t)64  * DIM_ + (T) * 64,    QA(BUF) + 8192  + ldst);         \
    gld16(gA + (size_t)128 * DIM_ + (T) * 64,    QA(BUF) + 16384 + ldst);         \
    gld16(gA + (size_t)192 * DIM_ + (T) * 64,    QA(BUF) + 24576 + ldst);         \
    gld16(gB + (size_t)(T) * 64,                 QB(BUF) + ldst);                 \
    gld16(gB + (size_t)64  * DIM_ + (T) * 64,    QB(BUF) + 8192  + ldst);         \
} while (0)

        STG6(0, 0);
        STG6(1, 1);
        asm volatile("s_waitcnt vmcnt(6)" ::: "memory");
        __builtin_amdgcn_s_barrier();

        for (int t = 0; t < NT_; ++t) {
            char* Ab = QA(t % 3);
            char* Bb = QB(t % 3);
            if (t < NT_ - 2) {
                STG6((t + 2) % 3, t + 2);
            }

            s16x8 fa0[4], fa1[4], fb0[4], fb1[4];
            #pragma unroll
            for (int mi = 0; mi < 4; ++mi) {
                fa0[mi] = *reinterpret_cast<const s16x8*>(&Ab[arow + mi * 2048 + off0]);
                fa1[mi] = *reinterpret_cast<const s16x8*>(&Ab[arow + mi * 2048 + off1]);
            }
            #pragma unroll
            for (int nf = 0; nf < 4; ++nf) {
                fb0[nf] = *reinterpret_cast<const s16x8*>(&Bb[brow + nf * 2048 + off0]);
                fb1[nf] = *reinterpret_cast<const s16x8*>(&Bb[brow + nf * 2048 + off1]);
            }

            __builtin_amdgcn_s_setprio(1);
            #pragma unroll
            for (int mi = 0; mi < 4; ++mi)
                #pragma unroll
                for (int nf = 0; nf < 4; ++nf)
                    acc[mi][nf] = MFMA(fa0[mi], fb0[nf], acc[mi][nf]);
            #pragma unroll
            for (int mi = 0; mi < 4; ++mi)
                #pragma unroll
                for (int nf = 0; nf < 4; ++nf)
                    acc[mi][nf] = MFMA(fa1[mi], fb1[nf], acc[mi][nf]);
            __builtin_amdgcn_s_setprio(0);

            if (t < NT_ - 2) {
                asm volatile("s_waitcnt vmcnt(6)" ::: "memory");
                __builtin_amdgcn_s_barrier();
            } else if (t == NT_ - 2) {
                asm volatile("s_waitcnt vmcnt(0)" ::: "memory");
                __builtin_amdgcn_s_barrier();
            }
        }
#undef STG6
#undef QA
#undef QB

        const float* mrow = mask + bb * L_;
        #pragma unroll
        for (int mf = 0; mf < 4; ++mf)
            #pragma unroll
            for (int rr = 0; rr < 4; ++rr) {
                int l = (rbase + mf * 16 + lg * 4 + rr) & (L_ - 1);
                float mvv = mrow[l];
                #pragma unroll
                for (int nf = 0; nf < 4; ++nf) {
                    int dc = cbase + nf * 16 + lr;
                    int h = dc >> 7, d = dc & 127;
                    q_ws[bh0 + (size_t)h * (L_ * DH_) + (size_t)l * DH_ + d]
                        = bf16_rne(acc[mf][nf][rr] * mvv);
                }
            }
    } else {
        // ---------------- KV GEMM (round-10 kvgemm body) ----------------
        // LDS: A = LDS + buf*32768 (2), Bk = LDS + 65536 + buf*16384 (2),
        //      Bv = LDS + 98304 + buf*16384 (2)
        const unsigned short* gA  = vb  + (size_t)(bm + srow) * DIM_ + scol;
        const unsigned short* gBk = wkb + (size_t)(bn + srow) * DIM_ + scol;
        const unsigned short* gBv = wvb + (size_t)(bn + srow) * DIM_ + scol;

        fp32x4 acck[4][4] = {};
        fp32x4 accv[4][4] = {};

#define KA(BUF)  (LDS + (BUF) * 32768)
#define KBK(BUF) (LDS + 65536 + (BUF) * 16384)
#define KBV(BUF) (LDS + 98304 + (BUF) * 16384)
#define STG8(BUF, T) do {                                                         \
    gld16(gA  + (size_t)(T) * 64,               KA(BUF) + ldst);                  \
    gld16(gA  + (size_t)64  * DIM_ + (T) * 64,  KA(BUF) + 8192  + ldst);          \
    gld16(gA  + (size_t)128 * DIM_ + (T) * 64,  KA(BUF) + 16384 + ldst);          \
    gld16(gA  + (size_t)192 * DIM_ + (T) * 64,  KA(BUF) + 24576 + ldst);          \
    gld16(gBk + (size_t)(T) * 64,               KBK(BUF) + ldst);                 \
    gld16(gBk + (size_t)64  * DIM_ + (T) * 64,  KBK(BUF) + 8192 + ldst);          \
    gld16(gBv + (size_t)(T) * 64,               KBV(BUF) + ldst);                 \
    gld16(gBv + (size_t)64  * DIM_ + (T) * 64,  KBV(BUF) + 8192 + ldst);          \
} while (0)

        STG8(0, 0);
        asm volatile("s_waitcnt vmcnt(0)" ::: "memory");
        __builtin_amdgcn_s_barrier();

        for (int t = 0; t < NT_; ++t) {
            const int buf = t & 1;
            if (t + 1 < NT_) STG8(buf ^ 1, t + 1);

            char* Ab  = KA(buf);
            char* Bkb = KBK(buf);
            char* Bvb = KBV(buf);

            #pragma unroll
            for (int kk = 0; kk < 2; ++kk) {
                const int o = kk ? off1 : off0;
                s16x8 fa[4], fk[4];
                #pragma unroll
                for (int mi = 0; mi < 4; ++mi)
                    fa[mi] = *reinterpret_cast<const s16x8*>(&Ab[arow + mi * 2048 + o]);
                #pragma unroll
                for (int nf = 0; nf < 4; ++nf)
                    fk[nf] = *reinterpret_cast<const s16x8*>(&Bkb[brow + nf * 2048 + o]);
                __builtin_amdgcn_s_setprio(1);
                #pragma unroll
                for (int mi = 0; mi < 4; ++mi)
                    #pragma unroll
                    for (int nf = 0; nf < 4; ++nf)
                        acck[mi][nf] = MFMA(fa[mi], fk[nf], acck[mi][nf]);
                __builtin_amdgcn_s_setprio(0);
                s16x8 fv[4];
                #pragma unroll
                for (int nf = 0; nf < 4; ++nf)
                    fv[nf] = *reinterpret_cast<const s16x8*>(&Bvb[brow + nf * 2048 + o]);
                __builtin_amdgcn_s_setprio(1);
                #pragma unroll
                for (int mi = 0; mi < 4; ++mi)
                    #pragma unroll
                    for (int nf = 0; nf < 4; ++nf)
                        accv[mi][nf] = MFMA(fa[mi], fv[nf], accv[mi][nf]);
                __builtin_amdgcn_s_setprio(0);
            }

            if (t + 1 < NT_) {
                asm volatile("s_waitcnt vmcnt(0)" ::: "memory");
                __builtin_amdgcn_s_barrier();
            }
        }
#undef STG8
#undef KA
#undef KBK
#undef KBV

        #pragma unroll
        for (int mf = 0; mf < 4; ++mf)
            #pragma unroll
            for (int rr = 0; rr < 4; ++rr) {
                int l = (rbase + mf * 16 + lg * 4 + rr) & (L_ - 1);
                #pragma unroll
                for (int nf = 0; nf < 4; ++nf) {
                    int dc = cbase + nf * 16 + lr;
                    int h = dc >> 7, d = dc & 127;
                    size_t off = bh0 + (size_t)h * (L_ * DH_)
                        + (size_t)(((l >> 4) * 4 + (d >> 5)) * 512
                        + ((l & 15) + (((d >> 3) & 3) << 4)) * 8 + (d & 7));
                    k_ws[off] = bf16_rne(acck[mf][nf][rr]);
                }
            }

        #pragma unroll
        for (int mf = 0; mf < 4; ++mf) {
            int l0 = (rbase + mf * 16 + lg * 4) & (L_ - 1);
            #pragma unroll
            for (int nf = 0; nf < 4; ++nf) {
                int dc = cbase + nf * 16 + lr;
                int h = dc >> 7, d = dc & 127;
                size_t off = bh0 + (size_t)h * (L_ * DH_)
                    + (size_t)(((l0 >> 5) * 8 + (d >> 4)) * 512
                    + ((d & 15) + (((l0 >> 3) & 3) << 4)) * 8 + (l0 & 7));
                ushort4 pk;
                pk.x = bf16_rne(accv[mf][nf][0]);
                pk.y = bf16_rne(accv[mf][nf][1]);
                pk.z = bf16_rne(accv[mf][nf][2]);
                pk.w = bf16_rne(accv[mf][nf][3]);
                *reinterpret_cast<ushort4*>(&v_ws[off]) = pk;
            }
        }
    }
}

// ---------------------------------------------------------------------------
// Attention (round-10 attn_fused3, verbatim — best measured: 76.3 us):
// swapped QK^T, cvt_pk P-pack, ones-MFMA rowsums, mask pre-folded into Q,
// K via global_load_lds dbuf, V frag-linear direct from global.
// ---------------------------------------------------------------------------
__global__ void __launch_bounds__(256, 2)
attn_fused3(const unsigned short* __restrict__ qw, const unsigned short* __restrict__ kfr,
            const unsigned short* __restrict__ vfr, float* __restrict__ out)
{
    __shared__ __align__(16) char Ks[2][16384];
    __shared__ __align__(16) char Pl[4][4608];

    const int tid  = threadIdx.x;
    const int lane = tid & 63;
    const int wid  = tid >> 6;
    const int lr   = lane & 15;
    const int lg   = lane >> 4;

    const int p  = (blockIdx.x & 7) * 64 + (blockIdx.x >> 3);
    const int bh = p >> 4;
    const int qt = p & 15;
    const int b  = bh >> 4;
    const int h  = bh & 15;
    const int q0 = qt * 128 + wid * 32;

    const unsigned short* qbase = qw  + (size_t)bh * (L_ * DH_);
    const unsigned short* kbase = kfr + (size_t)bh * (L_ * DH_);
    const unsigned short* vbase = vfr + (size_t)bh * (L_ * DH_);

    s16x8 qf[2][4];
    #pragma unroll
    for (int qs = 0; qs < 2; ++qs)
        #pragma unroll
        for (int kc = 0; kc < 4; ++kc)
            qf[qs][kc] = *reinterpret_cast<const s16x8*>(
                &qbase[(size_t)(q0 + qs * 16 + lr) * DH_ + kc * 32 + lg * 8]);

    s16x8 ones;
    #pragma unroll
    for (int i = 0; i < 8; ++i) ones[i] = (short)0x3F80;

    fp32x4 acc[2][8] = {};
    fp32x4 racc[2] = {};

    char* P = &Pl[wid][0];

    auto STAGE = [&](int buf, int t) {
        const unsigned short* g = kbase + (size_t)t * 8192;
        #pragma unroll
        for (int c = 0; c < 4; ++c)
            gld16(g + c * 2048 + tid * 8, &Ks[buf][c * 4096 + wid * 1024]);
    };

    STAGE(0, 0);
    __syncthreads();

    for (int t = 0; t < L_ / 64; ++t) {
        const int buf = t & 1;
        if (t + 1 < L_ / 64) STAGE(buf ^ 1, t + 1);

        s16x8 vv0[8], vv1[8];
        #pragma unroll
        for (int ds = 0; ds < 8; ++ds)
            vv0[ds] = *reinterpret_cast<const s16x8*>(
                &vbase[(size_t)t * 8192 + (0 * 8 + ds) * 512 + lane * 8]);

        fp32x4 s2[2][4] = {};
        __builtin_amdgcn_s_setprio(1);
        #pragma unroll
        for (int kvs = 0; kvs < 4; ++kvs)
            #pragma unroll
            for (int kc = 0; kc < 4; ++kc) {
                s16x8 kf = *reinterpret_cast<const s16x8*>(
                    Ks[buf] + (kvs * 4 + kc) * 1024 + lane * 16);
                s2[0][kvs] = MFMA(kf, qf[0][kc], s2[0][kvs]);
                s2[1][kvs] = MFMA(kf, qf[1][kc], s2[1][kvs]);
            }
        __builtin_amdgcn_s_setprio(0);

        #pragma unroll
        for (int qs = 0; qs < 2; ++qs)
            #pragma unroll
            for (int kvs = 0; kvs < 4; ++kvs) {
                float e0 = exp2_raw(s2[qs][kvs][0]);
                float e1 = exp2_raw(s2[qs][kvs][1]);
                float e2 = exp2_raw(s2[qs][kvs][2]);
                float e3 = exp2_raw(s2[qs][kvs][3]);
                uint2 pk;
                pk.x = cvtpk_bf16(e0, e1);
                pk.y = cvtpk_bf16(e2, e3);
                *reinterpret_cast<uint2*>(P + qs * 2304 + lr * 144 + kvs * 32 + lg * 8) = pk;
            }

        #pragma unroll
        for (int ds = 0; ds < 8; ++ds)
            vv1[ds] = *reinterpret_cast<const s16x8*>(
                &vbase[(size_t)t * 8192 + (1 * 8 + ds) * 512 + lane * 8]);

        __builtin_amdgcn_s_setprio(1);
        #pragma unroll
        for (int qs = 0; qs < 2; ++qs) {
            s16x8 pa0 = *reinterpret_cast<const s16x8*>(P + qs * 2304 + lr * 144 + 0 * 64 + lg * 16);
            s16x8 pa1 = *reinterpret_cast<const s16x8*>(P + qs * 2304 + lr * 144 + 1 * 64 + lg * 16);
            racc[qs] = MFMA(pa0, ones, racc[qs]);
            racc[qs] = MFMA(pa1, ones, racc[qs]);
            #pragma unroll
            for (int ds = 0; ds < 8; ++ds) {
                acc[qs][ds] = MFMA(pa0, vv0[ds], acc[qs][ds]);
                acc[qs][ds] = MFMA(pa1, vv1[ds], acc[qs][ds]);
            }
        }
        __builtin_amdgcn_s_setprio(0);

        __syncthreads();
    }

    #pragma unroll
    for (int qs = 0; qs < 2; ++qs) {
        float inv[4];
        #pragma unroll
        for (int r = 0; r < 4; ++r) inv[r] = 1.0f / racc[qs][r];
        #pragma unroll
        for (int ds = 0; ds < 8; ++ds)
            #pragma unroll
            for (int r = 0; r < 4; ++r)
                out[((size_t)(b * L_ + q0 + qs * 16 + lg * 4 + r)) * DIM_ + h * DH_ + ds * 16 + lr]
                    = acc[qs][ds][r] * inv[r];
    }
}

extern "C" void kernel_launch(void* const* d_in, const int* in_sizes, int n_in,
                              void* d_out, int out_size, void* d_ws, size_t ws_size,
                              hipStream_t stream) {
    const float* query = (const float*)d_in[0];
    const float* value = (const float*)d_in[1];
    const float* mask  = (const float*)d_in[2];
    const float* Wq    = (const float*)d_in[3];
    const float* Wk    = (const float*)d_in[4];
    const float* Wv    = (const float*)d_in[5];
    float* out = (float*)d_out;

    const size_t elems  = (size_t)B_ * H_ * L_ * DH_;  // 8388608
    const size_t welems = elems / 2;                   // 4194304
    unsigned short* q_ws = (unsigned short*)d_ws;
    unsigned short* k_ws = q_ws + elems;
    unsigned short* v_ws = k_ws + elems;

    unsigned short* qbf  = v_ws + elems;
    unsigned short* vbf  = qbf + elems;
    unsigned short* wqbf = vbf + elems;
    unsigned short* wkbf = wqbf + welems;
    unsigned short* wvbf = wkbf + welems;

    dim3 blk(256, 1, 1);

    cvt_all<<<dim3(2048, 1, 1), blk, 0, stream>>>(query, value, Wq, Wk, Wv,
                                                  qbf, vbf, wqbf, wkbf, wvbf);
    projgemm<<<dim3(512, 1, 1), dim3(512, 1, 1), 0, stream>>>(
        qbf, vbf, wqbf, wkbf, wvbf, mask, q_ws, k_ws, v_ws);

    attn_fused3<<<dim3(512, 1, 1), blk, 0, stream>>>(q_ws, k_ws, v_ws, out);
}

// Round 16
// 192.346 us; speedup vs baseline: 1.0822x; 1.0822x over previous
//
#include <hip/hip_runtime.h>
#include <hip/hip_bf16.h>
#include <stdint.h>

#define DIM_ 2048
#define L_   2048
#define B_   2
#define H_   16
#define DH_  128
#define NT_  32   // K tiles of 64

// scale folded into Wq: (1/sqrt(128)) * log2(e)  -> softmax uses raw v_exp_f32
#define QSCALE_ 0.12751743f

typedef __attribute__((ext_vector_type(4))) float fp32x4;
typedef __attribute__((ext_vector_type(8))) short s16x8;

__device__ __forceinline__ unsigned short bf16_rne(float f) {
    unsigned u = __builtin_bit_cast(unsigned, f);
    u += 0x7fffu + ((u >> 16) & 1u);
    return (unsigned short)(u >> 16);
}

__device__ __forceinline__ fp32x4 MFMA(s16x8 a, s16x8 b, fp32x4 c) {
    return __builtin_amdgcn_mfma_f32_16x16x32_bf16(a, b, c, 0, 0, 0);
}

__device__ __forceinline__ void gld16(const void* g, void* l) {
    auto gp = reinterpret_cast<const uint32_t __attribute__((address_space(1)))*>(
        reinterpret_cast<uintptr_t>(g));
    auto lp = reinterpret_cast<uint32_t __attribute__((address_space(3)))*>(
        reinterpret_cast<uintptr_t>(l));
    __builtin_amdgcn_global_load_lds(gp, lp, 16, 0, 0);
}

__device__ __forceinline__ float exp2_raw(float x) {
    float r; asm("v_exp_f32 %0, %1" : "=v"(r) : "v"(x)); return r;
}

__device__ __forceinline__ unsigned cvtpk_bf16(float a, float b) {
    unsigned r; asm("v_cvt_pk_bf16_f32 %0, %1, %2" : "=v"(r) : "v"(a), "v"(b)); return r;
}

// ---------------------------------------------------------------------------
// Merged f32->bf16 conversion: query | value | Wq(*QSCALE_) | Wk | Wv.
// Weights are re-read 16x by the GEMMs -> pre-conversion halves repeated
// traffic (round-14's in-GEMM conversion regressed for this reason).
// ---------------------------------------------------------------------------
__global__ void __launch_bounds__(256)
cvt_all(const float* __restrict__ query, const float* __restrict__ value,
        const float* __restrict__ Wq, const float* __restrict__ Wk,
        const float* __restrict__ Wv,
        unsigned short* __restrict__ qb, unsigned short* __restrict__ vb,
        unsigned short* __restrict__ wqb, unsigned short* __restrict__ wkb,
        unsigned short* __restrict__ wvb)
{
    const int total4 = 7340032;
    int i = blockIdx.x * 256 + threadIdx.x;
    const int stride = gridDim.x * 256;
    for (; i < total4; i += stride) {
        const float4* s; ushort4* d; int off; float sc = 1.0f;
        if (i < 2097152)      { s = (const float4*)query; d = (ushort4*)qb;  off = i; }
        else if (i < 4194304) { s = (const float4*)value; d = (ushort4*)vb;  off = i - 2097152; }
        else if (i < 5242880) { s = (const float4*)Wq;    d = (ushort4*)wqb; off = i - 4194304; sc = QSCALE_; }
        else if (i < 6291456) { s = (const float4*)Wk;    d = (ushort4*)wkb; off = i - 5242880; }
        else                  { s = (const float4*)Wv;    d = (ushort4*)wvb; off = i - 6291456; }
        float4 v = s[off];
        ushort4 o;
        o.x = bf16_rne(v.x * sc); o.y = bf16_rne(v.y * sc);
        o.z = bf16_rne(v.z * sc); o.w = bf16_rne(v.w * sc);
        d[off] = o;
    }
}

// ---------------------------------------------------------------------------
// Q projection GEMM: 256x128, triple-buffered, one barrier + counted
// vmcnt(6) per tile, full 3-bit both-sides chunk swizzle (0 bank conflicts).
// Grid 256 = 1 exact round. Mask folded into epilogue.
// ---------------------------------------------------------------------------
__global__ void __launch_bounds__(512, 2)
qgemm(const unsigned short* __restrict__ qb, const unsigned short* __restrict__ wqb,
      const float* __restrict__ mask, unsigned short* __restrict__ q_ws)
{
    __shared__ __align__(16) char As_[3][32768];
    __shared__ __align__(16) char Bs_[3][16384];

    const int tid  = threadIdx.x;
    const int lane = tid & 63;
    const int wid  = tid >> 6;
    const int wm   = wid >> 1;
    const int wn   = wid & 1;
    const int lr   = lane & 15;
    const int lg   = lane >> 4;

    const int rb = (blockIdx.x & 7) * 32 + (blockIdx.x >> 3);
    const int bm = (rb >> 4) << 8;
    const int bn = (rb & 15) << 7;

    const int srow = tid >> 3;
    const int scol = ((tid & 7) ^ ((tid >> 3) & 7)) * 8;
    const unsigned short* gA = qb  + (size_t)(bm + srow) * DIM_ + scol;
    const unsigned short* gB = wqb + (size_t)(bn + srow) * DIM_ + scol;
    const int ldst = wid * 1024;

    const int r7   = (lr & 7) << 4;
    const int arow = (wm * 64 + lr) * 128;
    const int brow = (wn * 64 + lr) * 128;
    const int off0 = (lg << 4) ^ r7;
    const int off1 = (64 | (lg << 4)) ^ r7;

    fp32x4 acc[4][4] = {};

#define STG6(SA, SB, T) do {                                                      \
    gld16(gA + (size_t)(T) * 64,                 (SA) + ldst);                    \
    gld16(gA + (size_t)64  * DIM_ + (T) * 64,    (SA) + 8192  + ldst);            \
    gld16(gA + (size_t)128 * DIM_ + (T) * 64,    (SA) + 16384 + ldst);            \
    gld16(gA + (size_t)192 * DIM_ + (T) * 64,    (SA) + 24576 + ldst);            \
    gld16(gB + (size_t)(T) * 64,                 (SB) + ldst);                    \
    gld16(gB + (size_t)64  * DIM_ + (T) * 64,    (SB) + 8192  + ldst);            \
} while (0)

    STG6(&As_[0][0], &Bs_[0][0], 0);
    STG6(&As_[1][0], &Bs_[1][0], 1);
    asm volatile("s_waitcnt vmcnt(6)" ::: "memory");
    __builtin_amdgcn_s_barrier();

    for (int t = 0; t < NT_; ++t) {
        char* Ab = &As_[t % 3][0];
        char* Bb = &Bs_[t % 3][0];
        if (t < NT_ - 2) {
            STG6(&As_[(t + 2) % 3][0], &Bs_[(t + 2) % 3][0], t + 2);
        }

        s16x8 fa0[4], fa1[4], fb0[4], fb1[4];
        #pragma unroll
        for (int mi = 0; mi < 4; ++mi) {
            fa0[mi] = *reinterpret_cast<const s16x8*>(&Ab[arow + mi * 2048 + off0]);
            fa1[mi] = *reinterpret_cast<const s16x8*>(&Ab[arow + mi * 2048 + off1]);
        }
        #pragma unroll
        for (int nf = 0; nf < 4; ++nf) {
            fb0[nf] = *reinterpret_cast<const s16x8*>(&Bb[brow + nf * 2048 + off0]);
            fb1[nf] = *reinterpret_cast<const s16x8*>(&Bb[brow + nf * 2048 + off1]);
        }

        __builtin_amdgcn_s_setprio(1);
        #pragma unroll
        for (int mi = 0; mi < 4; ++mi)
            #pragma unroll
            for (int nf = 0; nf < 4; ++nf)
                acc[mi][nf] = MFMA(fa0[mi], fb0[nf], acc[mi][nf]);
        #pragma unroll
        for (int mi = 0; mi < 4; ++mi)
            #pragma unroll
            for (int nf = 0; nf < 4; ++nf)
                acc[mi][nf] = MFMA(fa1[mi], fb1[nf], acc[mi][nf]);
        __builtin_amdgcn_s_setprio(0);

        if (t < NT_ - 2) {
            asm volatile("s_waitcnt vmcnt(6)" ::: "memory");
            __builtin_amdgcn_s_barrier();
        } else if (t == NT_ - 2) {
            asm volatile("s_waitcnt vmcnt(0)" ::: "memory");
            __builtin_amdgcn_s_barrier();
        }
    }
#undef STG6

    const int bb = bm >> 11;
    const size_t bh0 = (size_t)(bb * H_) * (L_ * DH_);
    const int rbase = bm + wm * 64;
    const int cbase = bn + wn * 64;
    const float* mrow = mask + bb * L_;

    #pragma unroll
    for (int mf = 0; mf < 4; ++mf)
        #pragma unroll
        for (int rr = 0; rr < 4; ++rr) {
            int l = (rbase + mf * 16 + lg * 4 + rr) & (L_ - 1);
            float mvv = mrow[l];
            #pragma unroll
            for (int nf = 0; nf < 4; ++nf) {
                int dc = cbase + nf * 16 + lr;
                int h = dc >> 7, d = dc & 127;
                q_ws[bh0 + (size_t)h * (L_ * DH_) + (size_t)l * DH_ + d]
                    = bf16_rne(acc[mf][nf][rr] * mvv);
            }
        }
}

// ---------------------------------------------------------------------------
// Fused K+V projection GEMM: A (value) staged ONCE per tile, both Wk and Wv
// B-tiles staged; 64 MFMA per 24 ds_reads per wave per K-tile.
// 2-phase schedule, one barrier/tile. Grid 256 = 1 exact round.
// ---------------------------------------------------------------------------
__global__ void __launch_bounds__(512, 2)
kvgemm(const unsigned short* __restrict__ vb, const unsigned short* __restrict__ wkb,
       const unsigned short* __restrict__ wvb,
       unsigned short* __restrict__ k_ws, unsigned short* __restrict__ v_ws)
{
    __shared__ __align__(16) char As_[2][32768];
    __shared__ __align__(16) char Bks_[2][16384];
    __shared__ __align__(16) char Bvs_[2][16384];

    const int tid  = threadIdx.x;
    const int lane = tid & 63;
    const int wid  = tid >> 6;
    const int wm   = wid >> 1;
    const int wn   = wid & 1;
    const int lr   = lane & 15;
    const int lg   = lane >> 4;

    const int rb = (blockIdx.x & 7) * 32 + (blockIdx.x >> 3);
    const int bm = (rb >> 4) << 8;
    const int bn = (rb & 15) << 7;

    const int srow = tid >> 3;
    const int scol = ((tid & 7) ^ ((tid >> 3) & 7)) * 8;
    const unsigned short* gA  = vb  + (size_t)(bm + srow) * DIM_ + scol;
    const unsigned short* gBk = wkb + (size_t)(bn + srow) * DIM_ + scol;
    const unsigned short* gBv = wvb + (size_t)(bn + srow) * DIM_ + scol;
    const int ldst = wid * 1024;

    const int r7   = (lr & 7) << 4;
    const int arow = (wm * 64 + lr) * 128;
    const int brow = (wn * 64 + lr) * 128;
    const int off0 = (lg << 4) ^ r7;
    const int off1 = (64 | (lg << 4)) ^ r7;

    fp32x4 acck[4][4] = {};
    fp32x4 accv[4][4] = {};

#define STG8(BUF, T) do {                                                         \
    gld16(gA  + (size_t)(T) * 64,               &As_[BUF][ldst]);                 \
    gld16(gA  + (size_t)64  * DIM_ + (T) * 64,  &As_[BUF][8192  + ldst]);         \
    gld16(gA  + (size_t)128 * DIM_ + (T) * 64,  &As_[BUF][16384 + ldst]);         \
    gld16(gA  + (size_t)192 * DIM_ + (T) * 64,  &As_[BUF][24576 + ldst]);         \
    gld16(gBk + (size_t)(T) * 64,               &Bks_[BUF][ldst]);                \
    gld16(gBk + (size_t)64  * DIM_ + (T) * 64,  &Bks_[BUF][8192 + ldst]);         \
    gld16(gBv + (size_t)(T) * 64,               &Bvs_[BUF][ldst]);                \
    gld16(gBv + (size_t)64  * DIM_ + (T) * 64,  &Bvs_[BUF][8192 + ldst]);         \
} while (0)

    STG8(0, 0);
    asm volatile("s_waitcnt vmcnt(0)" ::: "memory");
    __builtin_amdgcn_s_barrier();

    for (int t = 0; t < NT_; ++t) {
        const int buf = t & 1;
        if (t + 1 < NT_) STG8(buf ^ 1, t + 1);

        char* Ab  = &As_[buf][0];
        char* Bkb = &Bks_[buf][0];
        char* Bvb = &Bvs_[buf][0];

        #pragma unroll
        for (int kk = 0; kk < 2; ++kk) {
            const int o = kk ? off1 : off0;
            s16x8 fa[4], fk[4];
            #pragma unroll
            for (int mi = 0; mi < 4; ++mi)
                fa[mi] = *reinterpret_cast<const s16x8*>(&Ab[arow + mi * 2048 + o]);
            #pragma unroll
            for (int nf = 0; nf < 4; ++nf)
                fk[nf] = *reinterpret_cast<const s16x8*>(&Bkb[brow + nf * 2048 + o]);
            __builtin_amdgcn_s_setprio(1);
            #pragma unroll
            for (int mi = 0; mi < 4; ++mi)
                #pragma unroll
                for (int nf = 0; nf < 4; ++nf)
                    acck[mi][nf] = MFMA(fa[mi], fk[nf], acck[mi][nf]);
            __builtin_amdgcn_s_setprio(0);
            s16x8 fv[4];
            #pragma unroll
            for (int nf = 0; nf < 4; ++nf)
                fv[nf] = *reinterpret_cast<const s16x8*>(&Bvb[brow + nf * 2048 + o]);
            __builtin_amdgcn_s_setprio(1);
            #pragma unroll
            for (int mi = 0; mi < 4; ++mi)
                #pragma unroll
                for (int nf = 0; nf < 4; ++nf)
                    accv[mi][nf] = MFMA(fa[mi], fv[nf], accv[mi][nf]);
            __builtin_amdgcn_s_setprio(0);
        }

        if (t + 1 < NT_) {
            asm volatile("s_waitcnt vmcnt(0)" ::: "memory");
            __builtin_amdgcn_s_barrier();
        }
    }
#undef STG8

    const int bb = bm >> 11;
    const size_t bh0 = (size_t)(bb * H_) * (L_ * DH_);
    const int rbase = bm + wm * 64;
    const int cbase = bn + wn * 64;

    #pragma unroll
    for (int mf = 0; mf < 4; ++mf)
        #pragma unroll
        for (int rr = 0; rr < 4; ++rr) {
            int l = (rbase + mf * 16 + lg * 4 + rr) & (L_ - 1);
            #pragma unroll
            for (int nf = 0; nf < 4; ++nf) {
                int dc = cbase + nf * 16 + lr;
                int h = dc >> 7, d = dc & 127;
                size_t off = bh0 + (size_t)h * (L_ * DH_)
                    + (size_t)(((l >> 4) * 4 + (d >> 5)) * 512
                    + ((l & 15) + (((d >> 3) & 3) << 4)) * 8 + (d & 7));
                k_ws[off] = bf16_rne(acck[mf][nf][rr]);
            }
        }

    #pragma unroll
    for (int mf = 0; mf < 4; ++mf) {
        int l0 = (rbase + mf * 16 + lg * 4) & (L_ - 1);
        #pragma unroll
        for (int nf = 0; nf < 4; ++nf) {
            int dc = cbase + nf * 16 + lr;
            int h = dc >> 7, d = dc & 127;
            size_t off = bh0 + (size_t)h * (L_ * DH_)
                + (size_t)(((l0 >> 5) * 8 + (d >> 4)) * 512
                + ((d & 15) + (((l0 >> 3) & 3) << 4)) * 8 + (l0 & 7));
            ushort4 pk;
            pk.x = bf16_rne(accv[mf][nf][0]);
            pk.y = bf16_rne(accv[mf][nf][1]);
            pk.z = bf16_rne(accv[mf][nf][2]);
            pk.w = bf16_rne(accv[mf][nf][3]);
            *reinterpret_cast<ushort4*>(&v_ws[off]) = pk;
        }
    }
}

// ---------------------------------------------------------------------------
// Attention (round-10 attn_fused3, verbatim — best measured: 76.3 us):
// swapped QK^T, cvt_pk P-pack, ones-MFMA rowsums, mask pre-folded into Q,
// K via global_load_lds dbuf, V frag-linear direct from global.
// 32 q/wave x 2 waves/SIMD is the occupancy-vs-amortization optimum for
// this problem size (64K q-rows / 2048 resident waves).
// ---------------------------------------------------------------------------
__global__ void __launch_bounds__(256, 2)
attn_fused3(const unsigned short* __restrict__ qw, const unsigned short* __restrict__ kfr,
            const unsigned short* __restrict__ vfr, float* __restrict__ out)
{
    __shared__ __align__(16) char Ks[2][16384];
    __shared__ __align__(16) char Pl[4][4608];

    const int tid  = threadIdx.x;
    const int lane = tid & 63;
    const int wid  = tid >> 6;
    const int lr   = lane & 15;
    const int lg   = lane >> 4;

    const int p  = (blockIdx.x & 7) * 64 + (blockIdx.x >> 3);
    const int bh = p >> 4;
    const int qt = p & 15;
    const int b  = bh >> 4;
    const int h  = bh & 15;
    const int q0 = qt * 128 + wid * 32;

    const unsigned short* qbase = qw  + (size_t)bh * (L_ * DH_);
    const unsigned short* kbase = kfr + (size_t)bh * (L_ * DH_);
    const unsigned short* vbase = vfr + (size_t)bh * (L_ * DH_);

    s16x8 qf[2][4];
    #pragma unroll
    for (int qs = 0; qs < 2; ++qs)
        #pragma unroll
        for (int kc = 0; kc < 4; ++kc)
            qf[qs][kc] = *reinterpret_cast<const s16x8*>(
                &qbase[(size_t)(q0 + qs * 16 + lr) * DH_ + kc * 32 + lg * 8]);

    s16x8 ones;
    #pragma unroll
    for (int i = 0; i < 8; ++i) ones[i] = (short)0x3F80;

    fp32x4 acc[2][8] = {};
    fp32x4 racc[2] = {};

    char* P = &Pl[wid][0];

    auto STAGE = [&](int buf, int t) {
        const unsigned short* g = kbase + (size_t)t * 8192;
        #pragma unroll
        for (int c = 0; c < 4; ++c)
            gld16(g + c * 2048 + tid * 8, &Ks[buf][c * 4096 + wid * 1024]);
    };

    STAGE(0, 0);
    __syncthreads();

    for (int t = 0; t < L_ / 64; ++t) {
        const int buf = t & 1;
        if (t + 1 < L_ / 64) STAGE(buf ^ 1, t + 1);

        s16x8 vv0[8], vv1[8];
        #pragma unroll
        for (int ds = 0; ds < 8; ++ds)
            vv0[ds] = *reinterpret_cast<const s16x8*>(
                &vbase[(size_t)t * 8192 + (0 * 8 + ds) * 512 + lane * 8]);

        fp32x4 s2[2][4] = {};
        __builtin_amdgcn_s_setprio(1);
        #pragma unroll
        for (int kvs = 0; kvs < 4; ++kvs)
            #pragma unroll
            for (int kc = 0; kc < 4; ++kc) {
                s16x8 kf = *reinterpret_cast<const s16x8*>(
                    Ks[buf] + (kvs * 4 + kc) * 1024 + lane * 16);
                s2[0][kvs] = MFMA(kf, qf[0][kc], s2[0][kvs]);
                s2[1][kvs] = MFMA(kf, qf[1][kc], s2[1][kvs]);
            }
        __builtin_amdgcn_s_setprio(0);

        #pragma unroll
        for (int qs = 0; qs < 2; ++qs)
            #pragma unroll
            for (int kvs = 0; kvs < 4; ++kvs) {
                float e0 = exp2_raw(s2[qs][kvs][0]);
                float e1 = exp2_raw(s2[qs][kvs][1]);
                float e2 = exp2_raw(s2[qs][kvs][2]);
                float e3 = exp2_raw(s2[qs][kvs][3]);
                uint2 pk;
                pk.x = cvtpk_bf16(e0, e1);
                pk.y = cvtpk_bf16(e2, e3);
                *reinterpret_cast<uint2*>(P + qs * 2304 + lr * 144 + kvs * 32 + lg * 8) = pk;
            }

        #pragma unroll
        for (int ds = 0; ds < 8; ++ds)
            vv1[ds] = *reinterpret_cast<const s16x8*>(
                &vbase[(size_t)t * 8192 + (1 * 8 + ds) * 512 + lane * 8]);

        __builtin_amdgcn_s_setprio(1);
        #pragma unroll
        for (int qs = 0; qs < 2; ++qs) {
            s16x8 pa0 = *reinterpret_cast<const s16x8*>(P + qs * 2304 + lr * 144 + 0 * 64 + lg * 16);
            s16x8 pa1 = *reinterpret_cast<const s16x8*>(P + qs * 2304 + lr * 144 + 1 * 64 + lg * 16);
            racc[qs] = MFMA(pa0, ones, racc[qs]);
            racc[qs] = MFMA(pa1, ones, racc[qs]);
            #pragma unroll
            for (int ds = 0; ds < 8; ++ds) {
                acc[qs][ds] = MFMA(pa0, vv0[ds], acc[qs][ds]);
                acc[qs][ds] = MFMA(pa1, vv1[ds], acc[qs][ds]);
            }
        }
        __builtin_amdgcn_s_setprio(0);

        __syncthreads();
    }

    #pragma unroll
    for (int qs = 0; qs < 2; ++qs) {
        float inv[4];
        #pragma unroll
        for (int r = 0; r < 4; ++r) inv[r] = 1.0f / racc[qs][r];
        #pragma unroll
        for (int ds = 0; ds < 8; ++ds)
            #pragma unroll
            for (int r = 0; r < 4; ++r)
                out[((size_t)(b * L_ + q0 + qs * 16 + lg * 4 + r)) * DIM_ + h * DH_ + ds * 16 + lr]
                    = acc[qs][ds][r] * inv[r];
    }
}

extern "C" void kernel_launch(void* const* d_in, const int* in_sizes, int n_in,
                              void* d_out, int out_size, void* d_ws, size_t ws_size,
                              hipStream_t stream) {
    const float* query = (const float*)d_in[0];
    const float* value = (const float*)d_in[1];
    const float* mask  = (const float*)d_in[2];
    const float* Wq    = (const float*)d_in[3];
    const float* Wk    = (const float*)d_in[4];
    const float* Wv    = (const float*)d_in[5];
    float* out = (float*)d_out;

    const size_t elems  = (size_t)B_ * H_ * L_ * DH_;  // 8388608
    const size_t welems = elems / 2;                   // 4194304
    unsigned short* q_ws = (unsigned short*)d_ws;
    unsigned short* k_ws = q_ws + elems;
    unsigned short* v_ws = k_ws + elems;

    unsigned short* qbf  = v_ws + elems;
    unsigned short* vbf  = qbf + elems;
    unsigned short* wqbf = vbf + elems;
    unsigned short* wkbf = wqbf + welems;
    unsigned short* wvbf = wkbf + welems;

    dim3 blk(256, 1, 1);

    cvt_all<<<dim3(2048, 1, 1), blk, 0, stream>>>(query, value, Wq, Wk, Wv,
                                                  qbf, vbf, wqbf, wkbf, wvbf);
    qgemm<<<dim3(256, 1, 1), dim3(512, 1, 1), 0, stream>>>(qbf, wqbf, mask, q_ws);
    kvgemm<<<dim3(256, 1, 1), dim3(512, 1, 1), 0, stream>>>(vbf, wkbf, wvbf, k_ws, v_ws);

    attn_fused3<<<dim3(512, 1, 1), blk, 0, stream>>>(q_ws, k_ws, v_ws, out);
}